// Round 6
// baseline (246.199 us; speedup 1.0000x reference)
//
#include <hip/hip_runtime.h>

#define B_ 16
#define S_ 8192
#define D_ 128
#define C_ 64

// ---- legacy (atomic-fallback) ws layout, floats ----
#define WS_CNT_OFF   0
#define WS_KSUM_OFF  8192
#define WS_VSUM_OFF  (8192 + B_*C_*D_)
#define WS_CNTS_OFF  (8192 + 2*B_*C_*D_)

// ---- partial-store ws layout, floats ----
#define WS2_CNT_OFF   0
#define WS2_CNTS_OFF  8192
#define WS2_PART_OFF  24576
#define WS2_NEEDED_BYTES ((size_t)(24576 + 256 * 16384) * 4)

__global__ void normalize_centroids_k(const float* __restrict__ cen,
                                      float* __restrict__ cnT) {
    int tid = threadIdx.x;          // 512 threads, 1 block
    int c = tid >> 3;               // 0..63
    int l = tid & 7;                // 8 lanes per centroid
    float4 v[4];
    float s = 0.f;
#pragma unroll
    for (int q = 0; q < 4; ++q) {
        v[q] = *(const float4*)&cen[c * D_ + l * 16 + q * 4];
        s += v[q].x * v[q].x + v[q].y * v[q].y + v[q].z * v[q].z + v[q].w * v[q].w;
    }
#pragma unroll
    for (int m = 1; m < 8; m <<= 1) s += __shfl_xor(s, m, 8);
    float n = fmaxf(sqrtf(s), 1e-12f);
#pragma unroll
    for (int q = 0; q < 4; ++q) {
        int d = l * 16 + q * 4;
        cnT[(d + 0) * C_ + c] = v[q].x / n;
        cnT[(d + 1) * C_ + c] = v[q].y / n;
        cnT[(d + 2) * C_ + c] = v[q].z / n;
        cnT[(d + 3) * C_ + c] = v[q].w / n;
    }
}

// ---------------- Kernel A: sims + argmax -> assignments (float) -----------
// 256 thr, 128 rows/block, 8 lanes (tc) x 4 rows (A_TR) per thread.
// Depth-2 global prefetch; 5 blocks/CU (LDS-capped).
constexpr int A_THREADS = 256;
constexpr int A_TR = 4;                        // rows per thread
constexpr int A_ROWS = (A_THREADS / 8) * A_TR; // 128 rows per block
constexpr int A_NIT = D_ / 4;                  // 32 d-iterations

__global__ __launch_bounds__(A_THREADS, 5) void assign_k(
    const float* __restrict__ keys, const float* __restrict__ mask,
    const float* __restrict__ cnT_g, float* __restrict__ out_asg) {

    __shared__ float cnT[D_ * C_];   // 32 KB

    const int tid = threadIdx.x;
    for (int i = tid; i < D_ * C_; i += A_THREADS) cnT[i] = cnT_g[i];
    __syncthreads();

    const int tc  = tid & 7;          // cluster group: clusters tc*8 .. tc*8+7
    const int trt = tid >> 3;         // 0..31
    const size_t gr0 = (size_t)blockIdx.x * A_ROWS + (size_t)trt * A_TR;
    const float* kbase = keys + gr0 * D_;

    float acc[A_TR][8];
#pragma unroll
    for (int i = 0; i < A_TR; ++i)
#pragma unroll
        for (int j = 0; j < 8; ++j) acc[i][j] = 0.f;

    // FMA block for one 4-dim step using key regs kq[A_TR]
#define A_FMA_STEP(d0, kq)                                                    \
    {                                                                         \
        _Pragma("unroll")                                                     \
        for (int dd = 0; dd < 4; ++dd) {                                      \
            const float4 c0 = *(const float4*)&cnT[(d0 + dd) * C_ + tc * 8];  \
            const float4 c1 = *(const float4*)&cnT[(d0 + dd) * C_ + tc * 8 + 4]; \
            const float cw[8] = {c0.x, c0.y, c0.z, c0.w, c1.x, c1.y, c1.z, c1.w}; \
            _Pragma("unroll")                                                 \
            for (int i = 0; i < A_TR; ++i) {                                  \
                const float kv = dd == 0 ? kq[i].x : dd == 1 ? kq[i].y        \
                               : dd == 2 ? kq[i].z : kq[i].w;                 \
                _Pragma("unroll")                                             \
                for (int j = 0; j < 8; ++j)                                   \
                    acc[i][j] = fmaf(kv, cw[j], acc[i][j]);                   \
            }                                                                 \
        }                                                                     \
    }

#define A_LOAD(dst, it)                                                       \
    _Pragma("unroll")                                                         \
    for (int i = 0; i < A_TR; ++i)                                            \
        dst[i] = *(const float4*)(kbase + (size_t)i * D_ + (it) * 4);

    // depth-2 software pipeline, 2x unrolled main loop
    float4 k0[A_TR], k1[A_TR], k2[A_TR], k3[A_TR];
    A_LOAD(k0, 0)
    A_LOAD(k1, 1)
    for (int it = 0; it < A_NIT; it += 2) {
        if (it + 2 < A_NIT) A_LOAD(k2, it + 2) else {
#pragma unroll
            for (int i = 0; i < A_TR; ++i) k2[i] = k0[i];
        }
        A_FMA_STEP(it * 4, k0)
        if (it + 3 < A_NIT) A_LOAD(k3, it + 3) else {
#pragma unroll
            for (int i = 0; i < A_TR; ++i) k3[i] = k1[i];
        }
        A_FMA_STEP(it * 4 + 4, k1)
#pragma unroll
        for (int i = 0; i < A_TR; ++i) { k0[i] = k2[i]; k1[i] = k3[i]; }
    }
#undef A_FMA_STEP
#undef A_LOAD

    // per-row argmax across 8 tc lanes; first-max-index tie-break (jnp.argmax)
#pragma unroll
    for (int i = 0; i < A_TR; ++i) {
        float bv = acc[i][0];
        int bi = tc * 8;
#pragma unroll
        for (int j = 1; j < 8; ++j)
            if (acc[i][j] > bv) { bv = acc[i][j]; bi = tc * 8 + j; }
#pragma unroll
        for (int m = 1; m < 8; m <<= 1) {
            float ov = __shfl_xor(bv, m, 8);
            int   oi = __shfl_xor(bi, m, 8);
            if (ov > bv || (ov == bv && oi < bi)) { bv = ov; bi = oi; }
        }
        if (tc == 0) {
            float mv = mask[gr0 + i];
            out_asg[gr0 + i] = (float)((mv != 0.f) ? bi : 0);
        }
    }
}

// ---------------- Kernel B3: accumulate, NON-ATOMIC private regions --------
constexpr int B3_THREADS   = 512;
constexpr int B3_ROWS      = 512;          // rows per block
constexpr int B3_RPW       = B3_ROWS / 2;  // rows per wave (row-half)
constexpr int B3_NGRP      = B3_RPW / 8;   // 32 groups of 8 rows
constexpr int REG_STRIDE   = (C_ + 1) * 64;  // 4160 floats per region

__global__ __launch_bounds__(B3_THREADS, 1) void accum3_k(
    const float* __restrict__ keys, const float* __restrict__ values,
    const float* __restrict__ mask, const float* __restrict__ out_asg,
    float* __restrict__ g_part, float* __restrict__ g_cnts) {

    __shared__ float acc[8 * REG_STRIDE];   // 130 KB
    __shared__ float cntL[C_];
    __shared__ short cid[B3_ROWS];

    const int tid = threadIdx.x;
    for (int i = tid; i < 8 * REG_STRIDE; i += B3_THREADS) acc[i] = 0.f;
    if (tid < C_) cntL[tid] = 0.f;
    __syncthreads();

    const int bid = blockIdx.x;
    const int batch = bid >> 4;                 // 16 blocks per batch
    const int srow0 = (bid & 15) * B3_ROWS;
    const size_t rbase = (size_t)batch * S_ + srow0;

    // stage per-row cluster ids (sentinel C_ = masked out) + block counts
    {
        float mv = mask[rbase + tid];
        int a = (int)out_asg[rbase + tid];
        short s = (mv != 0.f) ? (short)a : (short)C_;
        cid[tid] = s;
        if (s < (short)C_) atomicAdd(&cntL[s], 1.f);
    }
    __syncthreads();

    const int w   = tid >> 6;
    const int l   = tid & 63;
    const int arr = w & 1;           // 0 = keys, 1 = values
    const int h   = (w >> 1) & 1;    // dim half
    const int r   = w >> 2;          // row half
    const float* src = (arr ? values : keys)
                       + (rbase + (size_t)r * B3_RPW) * D_ + h * 64 + l;
    float* aw = acc + ((arr * 2 + h) * 2 + r) * REG_STRIDE;
    const short* cbase = cid + r * B3_RPW;

    float v[8], vn[8];
#pragma unroll
    for (int j = 0; j < 8; ++j) v[j] = src[(size_t)j * D_];

    for (int g = 0; g < B3_NGRP; ++g) {
        if (g + 1 < B3_NGRP) {
#pragma unroll
            for (int j = 0; j < 8; ++j)
                vn[j] = src[(size_t)((g + 1) * 8 + j) * D_];
        }
        // 8 cluster ids via one 16B broadcast read
        int4 ci = *(const int4*)(cbase + g * 8);
        int c8[8];
        c8[0] = ci.x & 0xffff;  c8[1] = ci.x >> 16;
        c8[2] = ci.y & 0xffff;  c8[3] = ci.y >> 16;
        c8[4] = ci.z & 0xffff;  c8[5] = ci.z >> 16;
        c8[6] = ci.w & 0xffff;  c8[7] = ci.w >> 16;

        // merge duplicate cids into the first occurrence; duplicates -> dummy
#pragma unroll
        for (int j = 1; j < 8; ++j) {
            bool done = false;
#pragma unroll
            for (int i = 0; i < j; ++i) {
                bool eq = (c8[i] == c8[j]);
                v[i] += (eq && !done) ? v[j] : 0.f;
                done = done || eq;
            }
            c8[j] = done ? C_ : c8[j];
        }

        // batched non-atomic RMW: 8 reads, then 8 writes (distinct addresses)
        float old[8];
#pragma unroll
        for (int j = 0; j < 8; ++j) old[j] = aw[c8[j] * 64 + l];
#pragma unroll
        for (int j = 0; j < 8; ++j) aw[c8[j] * 64 + l] = old[j] + v[j];

#pragma unroll
        for (int j = 0; j < 8; ++j) v[j] = vn[j];
    }
    __syncthreads();

    // flush: sum the two row-half regions, store per-block partial
    float* pb = g_part + (size_t)bid * (2 * C_ * D_);
    for (int i = tid * 4; i < 2 * C_ * D_; i += B3_THREADS * 4) {
        const int ar = i >> 13;
        const int cd = i & (C_ * D_ - 1);
        const int c  = cd >> 7;
        const int d  = cd & 127;
        const int hh = d >> 6;
        const int dl = d & 63;
        const float* r0 = acc + ((ar * 2 + hh) * 2 + 0) * REG_STRIDE + c * 64 + dl;
        const float* r1 = acc + ((ar * 2 + hh) * 2 + 1) * REG_STRIDE + c * 64 + dl;
        float4 s0 = *(const float4*)r0;
        float4 s1 = *(const float4*)r1;
        float4 o;
        o.x = s0.x + s1.x; o.y = s0.y + s1.y;
        o.z = s0.z + s1.z; o.w = s0.w + s1.w;
        *(float4*)&pb[i] = o;
    }
    if (tid < C_) g_cnts[bid * C_ + tid] = cntL[tid];
}

// ---------------- Kernel C2: reduce partials + finalize --------------------
__global__ void finalize2_k(const float* __restrict__ ws,
                            const float* __restrict__ cen,
                            float* __restrict__ out) {
    int idx = blockIdx.x * blockDim.x + threadIdx.x;   // < B*C*D
    const int b  = idx >> 13;            // /8192
    const int cd = idx & (C_ * D_ - 1);
    const int c  = cd >> 7;
    const float* part = ws + WS2_PART_OFF;
    const float* cnts = ws + WS2_CNTS_OFF;

    float ks = 0.f, vs = 0.f, n = 0.f;
#pragma unroll
    for (int p = 0; p < 16; ++p) {
        const size_t pb = (size_t)(b * 16 + p) * (2 * C_ * D_);
        ks += part[pb + cd];
        vs += part[pb + C_ * D_ + cd];
        n  += cnts[(b * 16 + p) * C_ + c];
    }
    float cc, cv;
    if (n > 0.f) {
        cc = ks / n;
        cv = vs / n;
    } else {
        cc = cen[cd];
        cv = 0.f;
    }
    out[idx] = cc;
    out[B_ * C_ * D_ + idx] = cv;
}

// ---------------- fallback (atomic) path, used only if ws too small -------
constexpr int ACC_THREADS = 512;
constexpr int ACC_ROWS   = 256;
constexpr int ACC_NIT    = ACC_ROWS / 8;

__global__ __launch_bounds__(ACC_THREADS, 2) void accum_k(
    const float* __restrict__ keys, const float* __restrict__ values,
    const float* __restrict__ mask, const float* __restrict__ out_asg,
    float* __restrict__ g_ksum, float* __restrict__ g_vsum,
    float* __restrict__ g_cnt) {

    __shared__ float accK[C_ * D_];
    __shared__ float accV[C_ * D_];
    __shared__ float cntL[C_];
    __shared__ short cid[ACC_ROWS];

    const int tid = threadIdx.x;
    for (int i = tid; i < C_ * D_; i += ACC_THREADS) { accK[i] = 0.f; accV[i] = 0.f; }
    if (tid < C_) cntL[tid] = 0.f;
    __syncthreads();

    const int bid = blockIdx.x;
    const int batch = bid >> 5;
    const int srow0 = (bid & 31) * ACC_ROWS;
    const size_t rbase = (size_t)batch * S_ + srow0;

    if (tid < ACC_ROWS) {
        float mv = mask[rbase + tid];
        int a = (int)out_asg[rbase + tid];
        short s = (mv != 0.f) ? (short)a : (short)C_;
        cid[tid] = s;
        if (s < C_) atomicAdd(&cntL[s], 1.f);
    }
    __syncthreads();

    const int r_off = tid >> 6;
    const int half  = (tid >> 5) & 1;
    const int c4    = tid & 31;
    const float* src = (half ? values : keys) + (rbase + r_off) * D_ + c4 * 4;
    float* acc = half ? accV : accK;

    for (int it = 0; it < ACC_NIT; ++it) {
        float4 cur = *(const float4*)(src + (size_t)it * 8 * D_);
        const int a = cid[it * 8 + r_off];
        if (a < C_) {
            float* p = &acc[a * D_ + c4 * 4];
            atomicAdd(p + 0, cur.x);
            atomicAdd(p + 1, cur.y);
            atomicAdd(p + 2, cur.z);
            atomicAdd(p + 3, cur.w);
        }
    }
    __syncthreads();

    float* gks = g_ksum + (size_t)batch * C_ * D_;
    float* gvs = g_vsum + (size_t)batch * C_ * D_;
    for (int i = tid; i < C_ * D_; i += ACC_THREADS) {
        atomicAdd(&gks[i], accK[i]);
        atomicAdd(&gvs[i], accV[i]);
    }
    if (tid < C_) atomicAdd(&g_cnt[batch * C_ + tid], cntL[tid]);
}

__global__ void finalize_k(const float* __restrict__ ws,
                           const float* __restrict__ cen,
                           float* __restrict__ out) {
    int idx = blockIdx.x * blockDim.x + threadIdx.x;
    const float* ksum = ws + WS_KSUM_OFF;
    const float* vsum = ws + WS_VSUM_OFF;
    const float* cnt  = ws + WS_CNTS_OFF;
    int bc = idx >> 7;
    int cd = idx & (C_ * D_ - 1);
    float n = cnt[bc];
    float cc, cv;
    if (n > 0.f) {
        cc = ksum[idx] / n;
        cv = vsum[idx] / n;
    } else {
        cc = cen[cd];
        cv = 0.f;
    }
    out[idx] = cc;
    out[B_ * C_ * D_ + idx] = cv;
}

extern "C" void kernel_launch(void* const* d_in, const int* in_sizes, int n_in,
                              void* d_out, int out_size, void* d_ws, size_t ws_size,
                              hipStream_t stream) {
    const float* keys   = (const float*)d_in[0];
    const float* values = (const float*)d_in[1];
    const float* mask   = (const float*)d_in[2];
    const float* cen    = (const float*)d_in[3];
    float* ws  = (float*)d_ws;
    float* out = (float*)d_out;
    float* out_asg = out + 2 * B_ * C_ * D_;

    normalize_centroids_k<<<1, 512, 0, stream>>>(cen, ws + WS2_CNT_OFF);

    assign_k<<<(B_ * S_) / A_ROWS, A_THREADS, 0, stream>>>(
        keys, mask, ws + WS2_CNT_OFF, out_asg);

    if (ws_size >= WS2_NEEDED_BYTES) {
        accum3_k<<<(B_ * S_) / B3_ROWS, B3_THREADS, 0, stream>>>(
            keys, values, mask, out_asg,
            ws + WS2_PART_OFF, ws + WS2_CNTS_OFF);
        finalize2_k<<<(B_ * C_ * D_) / 256, 256, 0, stream>>>(ws, cen, out);
    } else {
        hipMemsetAsync(ws + WS_KSUM_OFF, 0,
                       (size_t)(2 * B_ * C_ * D_ + B_ * C_) * sizeof(float), stream);
        accum_k<<<(B_ * S_) / ACC_ROWS, ACC_THREADS, 0, stream>>>(
            keys, values, mask, out_asg,
            ws + WS_KSUM_OFF, ws + WS_VSUM_OFF, ws + WS_CNTS_OFF);
        finalize_k<<<(B_ * C_ * D_) / 256, 256, 0, stream>>>(ws, cen, out);
    }
}

// Round 7
// 135.942 us; speedup vs baseline: 1.8111x; 1.8111x over previous
//
#include <hip/hip_runtime.h>

#define B_ 16
#define S_ 8192
#define D_ 128
#define C_ 64

// ---- legacy (atomic-fallback) ws layout, floats ----
#define WS_CNT_OFF   0
#define WS_KSUM_OFF  8192
#define WS_VSUM_OFF  (8192 + B_*C_*D_)
#define WS_CNTS_OFF  (8192 + 2*B_*C_*D_)

// ---- partial-store ws layout, floats ----
#define WS2_CNT_OFF   0
#define WS2_CNTS_OFF  8192
#define WS2_PART_OFF  24576
#define WS2_NEEDED_BYTES ((size_t)(24576 + 256 * 16384) * 4)

__global__ void normalize_centroids_k(const float* __restrict__ cen,
                                      float* __restrict__ cnT) {
    int tid = threadIdx.x;          // 512 threads, 1 block
    int c = tid >> 3;               // 0..63
    int l = tid & 7;                // 8 lanes per centroid
    float4 v[4];
    float s = 0.f;
#pragma unroll
    for (int q = 0; q < 4; ++q) {
        v[q] = *(const float4*)&cen[c * D_ + l * 16 + q * 4];
        s += v[q].x * v[q].x + v[q].y * v[q].y + v[q].z * v[q].z + v[q].w * v[q].w;
    }
#pragma unroll
    for (int m = 1; m < 8; m <<= 1) s += __shfl_xor(s, m, 8);
    float n = fmaxf(sqrtf(s), 1e-12f);
#pragma unroll
    for (int q = 0; q < 4; ++q) {
        int d = l * 16 + q * 4;
        cnT[(d + 0) * C_ + c] = v[q].x / n;
        cnT[(d + 1) * C_ + c] = v[q].y / n;
        cnT[(d + 2) * C_ + c] = v[q].z / n;
        cnT[(d + 3) * C_ + c] = v[q].w / n;
    }
}

// ---------------- Kernel A: sims + argmax -> assignments (float) -----------
// 256 thr, 128 rows/block, 8 lanes (tc) x 4 rows (A_TR) per thread.
// Depth-2 global prefetch via 4 rotating buffers, tail peeled (no in-loop
// conditionals / copies). launch_bounds(256,4) keeps VGPR budget at 128
// so the ~112-VGPR pipeline does NOT spill (round-6 lesson).
constexpr int A_THREADS = 256;
constexpr int A_TR = 4;                        // rows per thread
constexpr int A_ROWS = (A_THREADS / 8) * A_TR; // 128 rows per block
constexpr int A_NIT = D_ / 4;                  // 32 d-iterations

__global__ __launch_bounds__(A_THREADS, 4) void assign_k(
    const float* __restrict__ keys, const float* __restrict__ mask,
    const float* __restrict__ cnT_g, float* __restrict__ out_asg) {

    __shared__ float cnT[D_ * C_];   // 32 KB

    const int tid = threadIdx.x;
    for (int i = tid; i < D_ * C_; i += A_THREADS) cnT[i] = cnT_g[i];
    __syncthreads();

    const int tc  = tid & 7;          // cluster group: clusters tc*8 .. tc*8+7
    const int trt = tid >> 3;         // 0..31
    const size_t gr0 = (size_t)blockIdx.x * A_ROWS + (size_t)trt * A_TR;
    const float* kbase = keys + gr0 * D_;

    float acc[A_TR][8];
#pragma unroll
    for (int i = 0; i < A_TR; ++i)
#pragma unroll
        for (int j = 0; j < 8; ++j) acc[i][j] = 0.f;

#define A_FMA_STEP(d0, kq)                                                    \
    {                                                                         \
        _Pragma("unroll")                                                     \
        for (int dd = 0; dd < 4; ++dd) {                                      \
            const float4 c0 = *(const float4*)&cnT[(d0 + dd) * C_ + tc * 8];  \
            const float4 c1 = *(const float4*)&cnT[(d0 + dd) * C_ + tc * 8 + 4]; \
            const float cw[8] = {c0.x, c0.y, c0.z, c0.w, c1.x, c1.y, c1.z, c1.w}; \
            _Pragma("unroll")                                                 \
            for (int i = 0; i < A_TR; ++i) {                                  \
                const float kv = dd == 0 ? kq[i].x : dd == 1 ? kq[i].y        \
                               : dd == 2 ? kq[i].z : kq[i].w;                 \
                _Pragma("unroll")                                             \
                for (int j = 0; j < 8; ++j)                                   \
                    acc[i][j] = fmaf(kv, cw[j], acc[i][j]);                   \
            }                                                                 \
        }                                                                     \
    }

#define A_LOAD(dst, it)                                                       \
    {                                                                         \
        _Pragma("unroll")                                                     \
        for (int i = 0; i < A_TR; ++i)                                        \
            dst[i] = *(const float4*)(kbase + (size_t)i * D_ + (it) * 4);     \
    }

    // 4-buffer rotation: while computing k0,k1 the loads for k2,k3 are in
    // flight and vice versa. A_NIT = 32, main loop runs it = 0..24.
    float4 k0[A_TR], k1[A_TR], k2[A_TR], k3[A_TR];
    A_LOAD(k0, 0)
    A_LOAD(k1, 1)
    int it = 0;
    for (; it + 4 < A_NIT; it += 4) {
        A_LOAD(k2, it + 2)
        A_FMA_STEP((it + 0) * 4, k0)
        A_LOAD(k3, it + 3)
        A_FMA_STEP((it + 1) * 4, k1)
        A_LOAD(k0, it + 4)
        A_FMA_STEP((it + 2) * 4, k2)
        A_LOAD(k1, it + 5)
        A_FMA_STEP((it + 3) * 4, k3)
    }
    // tail: it == 28; two loads remain (30, 31), four FMA steps remain
    A_LOAD(k2, it + 2)
    A_FMA_STEP((it + 0) * 4, k0)
    A_LOAD(k3, it + 3)
    A_FMA_STEP((it + 1) * 4, k1)
    A_FMA_STEP((it + 2) * 4, k2)
    A_FMA_STEP((it + 3) * 4, k3)
#undef A_FMA_STEP
#undef A_LOAD

    // per-row argmax across 8 tc lanes; first-max-index tie-break (jnp.argmax)
#pragma unroll
    for (int i = 0; i < A_TR; ++i) {
        float bv = acc[i][0];
        int bi = tc * 8;
#pragma unroll
        for (int j = 1; j < 8; ++j)
            if (acc[i][j] > bv) { bv = acc[i][j]; bi = tc * 8 + j; }
#pragma unroll
        for (int m = 1; m < 8; m <<= 1) {
            float ov = __shfl_xor(bv, m, 8);
            int   oi = __shfl_xor(bi, m, 8);
            if (ov > bv || (ov == bv && oi < bi)) { bv = ov; bi = oi; }
        }
        if (tc == 0) {
            float mv = mask[gr0 + i];
            out_asg[gr0 + i] = (float)((mv != 0.f) ? bi : 0);
        }
    }
}

// ---------------- Kernel B3: accumulate, NON-ATOMIC private regions --------
constexpr int B3_THREADS   = 512;
constexpr int B3_ROWS      = 512;          // rows per block
constexpr int B3_RPW       = B3_ROWS / 2;  // rows per wave (row-half)
constexpr int B3_NGRP      = B3_RPW / 8;   // 32 groups of 8 rows
constexpr int REG_STRIDE   = (C_ + 1) * 64;  // 4160 floats per region

__global__ __launch_bounds__(B3_THREADS, 1) void accum3_k(
    const float* __restrict__ keys, const float* __restrict__ values,
    const float* __restrict__ mask, const float* __restrict__ out_asg,
    float* __restrict__ g_part, float* __restrict__ g_cnts) {

    __shared__ float acc[8 * REG_STRIDE];   // 130 KB
    __shared__ float cntL[C_];
    __shared__ short cid[B3_ROWS];

    const int tid = threadIdx.x;
    for (int i = tid; i < 8 * REG_STRIDE; i += B3_THREADS) acc[i] = 0.f;
    if (tid < C_) cntL[tid] = 0.f;
    __syncthreads();

    const int bid = blockIdx.x;
    const int batch = bid >> 4;                 // 16 blocks per batch
    const int srow0 = (bid & 15) * B3_ROWS;
    const size_t rbase = (size_t)batch * S_ + srow0;

    // stage per-row cluster ids (sentinel C_ = masked out) + block counts
    {
        float mv = mask[rbase + tid];
        int a = (int)out_asg[rbase + tid];
        short s = (mv != 0.f) ? (short)a : (short)C_;
        cid[tid] = s;
        if (s < (short)C_) atomicAdd(&cntL[s], 1.f);
    }
    __syncthreads();

    const int w   = tid >> 6;
    const int l   = tid & 63;
    const int arr = w & 1;           // 0 = keys, 1 = values
    const int h   = (w >> 1) & 1;    // dim half
    const int r   = w >> 2;          // row half
    const float* src = (arr ? values : keys)
                       + (rbase + (size_t)r * B3_RPW) * D_ + h * 64 + l;
    float* aw = acc + ((arr * 2 + h) * 2 + r) * REG_STRIDE;
    const short* cbase = cid + r * B3_RPW;

    float v[8], vn[8];
#pragma unroll
    for (int j = 0; j < 8; ++j) v[j] = src[(size_t)j * D_];

    for (int g = 0; g < B3_NGRP; ++g) {
        if (g + 1 < B3_NGRP) {
#pragma unroll
            for (int j = 0; j < 8; ++j)
                vn[j] = src[(size_t)((g + 1) * 8 + j) * D_];
        }
        // 8 cluster ids via one 16B broadcast read
        int4 ci = *(const int4*)(cbase + g * 8);
        int c8[8];
        c8[0] = ci.x & 0xffff;  c8[1] = ci.x >> 16;
        c8[2] = ci.y & 0xffff;  c8[3] = ci.y >> 16;
        c8[4] = ci.z & 0xffff;  c8[5] = ci.z >> 16;
        c8[6] = ci.w & 0xffff;  c8[7] = ci.w >> 16;

        // merge duplicate cids into the first occurrence; duplicates -> dummy
#pragma unroll
        for (int j = 1; j < 8; ++j) {
            bool done = false;
#pragma unroll
            for (int i = 0; i < j; ++i) {
                bool eq = (c8[i] == c8[j]);
                v[i] += (eq && !done) ? v[j] : 0.f;
                done = done || eq;
            }
            c8[j] = done ? C_ : c8[j];
        }

        // batched non-atomic RMW: 8 reads, then 8 writes (distinct addresses)
        float old[8];
#pragma unroll
        for (int j = 0; j < 8; ++j) old[j] = aw[c8[j] * 64 + l];
#pragma unroll
        for (int j = 0; j < 8; ++j) aw[c8[j] * 64 + l] = old[j] + v[j];

#pragma unroll
        for (int j = 0; j < 8; ++j) v[j] = vn[j];
    }
    __syncthreads();

    // flush: sum the two row-half regions, store per-block partial
    float* pb = g_part + (size_t)bid * (2 * C_ * D_);
    for (int i = tid * 4; i < 2 * C_ * D_; i += B3_THREADS * 4) {
        const int ar = i >> 13;
        const int cd = i & (C_ * D_ - 1);
        const int c  = cd >> 7;
        const int d  = cd & 127;
        const int hh = d >> 6;
        const int dl = d & 63;
        const float* r0 = acc + ((ar * 2 + hh) * 2 + 0) * REG_STRIDE + c * 64 + dl;
        const float* r1 = acc + ((ar * 2 + hh) * 2 + 1) * REG_STRIDE + c * 64 + dl;
        float4 s0 = *(const float4*)r0;
        float4 s1 = *(const float4*)r1;
        float4 o;
        o.x = s0.x + s1.x; o.y = s0.y + s1.y;
        o.z = s0.z + s1.z; o.w = s0.w + s1.w;
        *(float4*)&pb[i] = o;
    }
    if (tid < C_) g_cnts[bid * C_ + tid] = cntL[tid];
}

// ---------------- Kernel C2: reduce partials + finalize --------------------
__global__ void finalize2_k(const float* __restrict__ ws,
                            const float* __restrict__ cen,
                            float* __restrict__ out) {
    int idx = blockIdx.x * blockDim.x + threadIdx.x;   // < B*C*D
    const int b  = idx >> 13;            // /8192
    const int cd = idx & (C_ * D_ - 1);
    const int c  = cd >> 7;
    const float* part = ws + WS2_PART_OFF;
    const float* cnts = ws + WS2_CNTS_OFF;

    float ks = 0.f, vs = 0.f, n = 0.f;
#pragma unroll
    for (int p = 0; p < 16; ++p) {
        const size_t pb = (size_t)(b * 16 + p) * (2 * C_ * D_);
        ks += part[pb + cd];
        vs += part[pb + C_ * D_ + cd];
        n  += cnts[(b * 16 + p) * C_ + c];
    }
    float cc, cv;
    if (n > 0.f) {
        cc = ks / n;
        cv = vs / n;
    } else {
        cc = cen[cd];
        cv = 0.f;
    }
    out[idx] = cc;
    out[B_ * C_ * D_ + idx] = cv;
}

// ---------------- fallback (atomic) path, used only if ws too small -------
constexpr int ACC_THREADS = 512;
constexpr int ACC_ROWS   = 256;
constexpr int ACC_NIT    = ACC_ROWS / 8;

__global__ __launch_bounds__(ACC_THREADS, 2) void accum_k(
    const float* __restrict__ keys, const float* __restrict__ values,
    const float* __restrict__ mask, const float* __restrict__ out_asg,
    float* __restrict__ g_ksum, float* __restrict__ g_vsum,
    float* __restrict__ g_cnt) {

    __shared__ float accK[C_ * D_];
    __shared__ float accV[C_ * D_];
    __shared__ float cntL[C_];
    __shared__ short cid[ACC_ROWS];

    const int tid = threadIdx.x;
    for (int i = tid; i < C_ * D_; i += ACC_THREADS) { accK[i] = 0.f; accV[i] = 0.f; }
    if (tid < C_) cntL[tid] = 0.f;
    __syncthreads();

    const int bid = blockIdx.x;
    const int batch = bid >> 5;
    const int srow0 = (bid & 31) * ACC_ROWS;
    const size_t rbase = (size_t)batch * S_ + srow0;

    if (tid < ACC_ROWS) {
        float mv = mask[rbase + tid];
        int a = (int)out_asg[rbase + tid];
        short s = (mv != 0.f) ? (short)a : (short)C_;
        cid[tid] = s;
        if (s < C_) atomicAdd(&cntL[s], 1.f);
    }
    __syncthreads();

    const int r_off = tid >> 6;
    const int half  = (tid >> 5) & 1;
    const int c4    = tid & 31;
    const float* src = (half ? values : keys) + (rbase + r_off) * D_ + c4 * 4;
    float* acc = half ? accV : accK;

    for (int it = 0; it < ACC_NIT; ++it) {
        float4 cur = *(const float4*)(src + (size_t)it * 8 * D_);
        const int a = cid[it * 8 + r_off];
        if (a < C_) {
            float* p = &acc[a * D_ + c4 * 4];
            atomicAdd(p + 0, cur.x);
            atomicAdd(p + 1, cur.y);
            atomicAdd(p + 2, cur.z);
            atomicAdd(p + 3, cur.w);
        }
    }
    __syncthreads();

    float* gks = g_ksum + (size_t)batch * C_ * D_;
    float* gvs = g_vsum + (size_t)batch * C_ * D_;
    for (int i = tid; i < C_ * D_; i += ACC_THREADS) {
        atomicAdd(&gks[i], accK[i]);
        atomicAdd(&gvs[i], accV[i]);
    }
    if (tid < C_) atomicAdd(&g_cnt[batch * C_ + tid], cntL[tid]);
}

__global__ void finalize_k(const float* __restrict__ ws,
                           const float* __restrict__ cen,
                           float* __restrict__ out) {
    int idx = blockIdx.x * blockDim.x + threadIdx.x;
    const float* ksum = ws + WS_KSUM_OFF;
    const float* vsum = ws + WS_VSUM_OFF;
    const float* cnt  = ws + WS_CNTS_OFF;
    int bc = idx >> 7;
    int cd = idx & (C_ * D_ - 1);
    float n = cnt[bc];
    float cc, cv;
    if (n > 0.f) {
        cc = ksum[idx] / n;
        cv = vsum[idx] / n;
    } else {
        cc = cen[cd];
        cv = 0.f;
    }
    out[idx] = cc;
    out[B_ * C_ * D_ + idx] = cv;
}

extern "C" void kernel_launch(void* const* d_in, const int* in_sizes, int n_in,
                              void* d_out, int out_size, void* d_ws, size_t ws_size,
                              hipStream_t stream) {
    const float* keys   = (const float*)d_in[0];
    const float* values = (const float*)d_in[1];
    const float* mask   = (const float*)d_in[2];
    const float* cen    = (const float*)d_in[3];
    float* ws  = (float*)d_ws;
    float* out = (float*)d_out;
    float* out_asg = out + 2 * B_ * C_ * D_;

    normalize_centroids_k<<<1, 512, 0, stream>>>(cen, ws + WS2_CNT_OFF);

    assign_k<<<(B_ * S_) / A_ROWS, A_THREADS, 0, stream>>>(
        keys, mask, ws + WS2_CNT_OFF, out_asg);

    if (ws_size >= WS2_NEEDED_BYTES) {
        accum3_k<<<(B_ * S_) / B3_ROWS, B3_THREADS, 0, stream>>>(
            keys, values, mask, out_asg,
            ws + WS2_PART_OFF, ws + WS2_CNTS_OFF);
        finalize2_k<<<(B_ * C_ * D_) / 256, 256, 0, stream>>>(ws, cen, out);
    } else {
        hipMemsetAsync(ws + WS_KSUM_OFF, 0,
                       (size_t)(2 * B_ * C_ * D_ + B_ * C_) * sizeof(float), stream);
        accum_k<<<(B_ * S_) / ACC_ROWS, ACC_THREADS, 0, stream>>>(
            keys, values, mask, out_asg,
            ws + WS_KSUM_OFF, ws + WS_VSUM_OFF, ws + WS_CNTS_OFF);
        finalize_k<<<(B_ * C_ * D_) / 256, 256, 0, stream>>>(ws, cen, out);
    }
}

// Round 8
// 77.597 us; speedup vs baseline: 3.1728x; 1.7519x over previous
//
#include <hip/hip_runtime.h>

#define B_ 16
#define S_ 8192
#define D_ 128
#define C_ 64

// ---- legacy (atomic-fallback) ws layout, floats ----
#define WS_CNT_OFF   0
#define WS_KSUM_OFF  8192
#define WS_VSUM_OFF  (8192 + B_*C_*D_)
#define WS_CNTS_OFF  (8192 + 2*B_*C_*D_)

// ---- partial-store ws layout, floats ----
// [0,8192)    cn2[w][s][dd][c8]  (normalized centroids, wave-grouped)
// [8192,..)   per-block counts [256][64]; partials [256][16384]
#define WS2_CNT_OFF   0
#define WS2_CNTS_OFF  8192
#define WS2_PART_OFF  24576
#define WS2_NEEDED_BYTES ((size_t)(24576 + 256 * 16384) * 4)

// cn2 layout: [w 0..7][s 0..31][dd 0..3][c8 0..7]  (cluster = w*8+c8, dim = s*4+dd)
__global__ void normalize_centroids_k(const float* __restrict__ cen,
                                      float* __restrict__ cn2) {
    int tid = threadIdx.x;          // 512 threads, 1 block
    int c = tid >> 3;               // 0..63
    int lq = tid & 7;               // 8 lanes per centroid, 16 dims each
    float4 v[4];
    float s = 0.f;
#pragma unroll
    for (int q = 0; q < 4; ++q) {
        v[q] = *(const float4*)&cen[c * D_ + lq * 16 + q * 4];
        s += v[q].x * v[q].x + v[q].y * v[q].y + v[q].z * v[q].z + v[q].w * v[q].w;
    }
#pragma unroll
    for (int m = 1; m < 8; m <<= 1) s += __shfl_xor(s, m, 8);
    float n = fmaxf(sqrtf(s), 1e-12f);
    const int w  = c >> 3;
    const int c8 = c & 7;
#pragma unroll
    for (int q = 0; q < 4; ++q) {
        const int st = lq * 4 + q;             // dim step = d>>2
        float comp[4] = {v[q].x, v[q].y, v[q].z, v[q].w};
#pragma unroll
        for (int dd = 0; dd < 4; ++dd)
            cn2[(w * 32 + st) * 32 + dd * 8 + c8] = comp[dd] / n;
    }
}

// ---------------- Kernel A2: sims + argmax, wave-per-cluster-group ---------
// 512 thr = 8 waves; wave w owns clusters [8w, 8w+8); each lane owns 1 row.
// Keys staged in LDS with XOR column swizzle (slot = dg ^ (row&31)) ->
// per-step ds_read_b128 is phase-balanced. Centroids read wave-uniform
// from cn2 (scalarizable). acc = 8 VGPR/lane -> high occupancy, TLP
// hides everything (round 6/7 lesson: no register-hungry pipelines).
constexpr int A2_THREADS = 512;
constexpr int A2_ROWS    = 64;     // rows per block (1 per lane)

__global__ void assign2_k(const float* __restrict__ keys,
                          const float* __restrict__ mask,
                          const float* __restrict__ cn2,
                          float* __restrict__ out_asg) {

    __shared__ float4 kT[A2_ROWS * 32];   // 32 KB, swizzled
    __shared__ float cvL[8][A2_ROWS];
    __shared__ int   ciL[8][A2_ROWS];

    const int tid = threadIdx.x;
    const size_t row0 = (size_t)blockIdx.x * A2_ROWS;

    // stage keys: linear LDS slot L; physical col slot = L&31 holds
    // logical col (slot ^ (row&31)) -> read side applies same XOR.
    const float4* kg = (const float4*)keys + row0 * 32;
#pragma unroll
    for (int r = 0; r < (A2_ROWS * 32) / A2_THREADS; ++r) {   // 4 iters
        int L = r * A2_THREADS + tid;
        int row = L >> 5, slot = L & 31;
        kT[L] = kg[row * 32 + (slot ^ (row & 31))];
    }
    __syncthreads();

    const int w = __builtin_amdgcn_readfirstlane(tid >> 6);   // wave id, uniform
    const int l = tid & 63;                                   // row within block
    const int lx = l & 31;
    const float* cnw = cn2 + w * 1024;    // [s][dd][c8], 32 floats per step

    float acc[8];
#pragma unroll
    for (int c = 0; c < 8; ++c) acc[c] = 0.f;

    float4 kc = kT[l * 32 + (0 ^ lx)];
    for (int s = 0; s < 31; ++s) {
        float4 kn = kT[l * 32 + ((s + 1) ^ lx)];
        float cs[32];
#pragma unroll
        for (int i = 0; i < 8; ++i)
            *(float4*)&cs[i * 4] = *(const float4*)&cnw[s * 32 + i * 4];
#pragma unroll
        for (int dd = 0; dd < 4; ++dd) {
            const float kv = dd == 0 ? kc.x : dd == 1 ? kc.y
                           : dd == 2 ? kc.z : kc.w;
#pragma unroll
            for (int c = 0; c < 8; ++c)
                acc[c] = fmaf(kv, cs[dd * 8 + c], acc[c]);
        }
        kc = kn;
    }
    {   // s = 31 (peeled tail)
        float cs[32];
#pragma unroll
        for (int i = 0; i < 8; ++i)
            *(float4*)&cs[i * 4] = *(const float4*)&cnw[31 * 32 + i * 4];
#pragma unroll
        for (int dd = 0; dd < 4; ++dd) {
            const float kv = dd == 0 ? kc.x : dd == 1 ? kc.y
                           : dd == 2 ? kc.z : kc.w;
#pragma unroll
            for (int c = 0; c < 8; ++c)
                acc[c] = fmaf(kv, cs[dd * 8 + c], acc[c]);
        }
    }

    // in-lane argmax over this wave's 8 clusters (ascending, strict >)
    float bv = acc[0];
    int bj = 0;
#pragma unroll
    for (int j = 1; j < 8; ++j)
        if (acc[j] > bv) { bv = acc[j]; bj = j; }
    cvL[w][l] = bv;
    ciL[w][l] = w * 8 + bj;
    __syncthreads();

    // cross-wave reduce (ascending w, strict > keeps lowest cluster on tie)
    if (tid < A2_ROWS) {
        float rbv = cvL[0][tid];
        int rbi = ciL[0][tid];
#pragma unroll
        for (int ww = 1; ww < 8; ++ww) {
            float v = cvL[ww][tid];
            int ii = ciL[ww][tid];
            if (v > rbv) { rbv = v; rbi = ii; }
        }
        float mv = mask[row0 + tid];
        out_asg[row0 + tid] = (mv != 0.f) ? (float)rbi : 0.f;
    }
}

// ---------------- Kernel B3: accumulate, NON-ATOMIC private regions --------
constexpr int B3_THREADS   = 512;
constexpr int B3_ROWS      = 512;          // rows per block
constexpr int B3_RPW       = B3_ROWS / 2;  // rows per wave (row-half)
constexpr int B3_NGRP      = B3_RPW / 8;   // 32 groups of 8 rows
constexpr int REG_STRIDE   = (C_ + 1) * 64;  // 4160 floats per region

__global__ __launch_bounds__(B3_THREADS, 1) void accum3_k(
    const float* __restrict__ keys, const float* __restrict__ values,
    const float* __restrict__ mask, const float* __restrict__ out_asg,
    float* __restrict__ g_part, float* __restrict__ g_cnts) {

    __shared__ float acc[8 * REG_STRIDE];   // 130 KB
    __shared__ float cntL[C_];
    __shared__ short cid[B3_ROWS];

    const int tid = threadIdx.x;
    for (int i = tid; i < 8 * REG_STRIDE; i += B3_THREADS) acc[i] = 0.f;
    if (tid < C_) cntL[tid] = 0.f;
    __syncthreads();

    const int bid = blockIdx.x;
    const int batch = bid >> 4;                 // 16 blocks per batch
    const int srow0 = (bid & 15) * B3_ROWS;
    const size_t rbase = (size_t)batch * S_ + srow0;

    // stage per-row cluster ids (sentinel C_ = masked out) + block counts
    {
        float mv = mask[rbase + tid];
        int a = (int)out_asg[rbase + tid];
        short s = (mv != 0.f) ? (short)a : (short)C_;
        cid[tid] = s;
        if (s < (short)C_) atomicAdd(&cntL[s], 1.f);
    }
    __syncthreads();

    const int w   = tid >> 6;
    const int l   = tid & 63;
    const int arr = w & 1;           // 0 = keys, 1 = values
    const int h   = (w >> 1) & 1;    // dim half
    const int r   = w >> 2;          // row half
    const float* src = (arr ? values : keys)
                       + (rbase + (size_t)r * B3_RPW) * D_ + h * 64 + l;
    float* aw = acc + ((arr * 2 + h) * 2 + r) * REG_STRIDE;
    const short* cbase = cid + r * B3_RPW;

    float v[8], vn[8];
#pragma unroll
    for (int j = 0; j < 8; ++j) v[j] = src[(size_t)j * D_];

    for (int g = 0; g < B3_NGRP; ++g) {
        if (g + 1 < B3_NGRP) {
#pragma unroll
            for (int j = 0; j < 8; ++j)
                vn[j] = src[(size_t)((g + 1) * 8 + j) * D_];
        }
        // 8 cluster ids via one 16B broadcast read
        int4 ci = *(const int4*)(cbase + g * 8);
        int c8[8];
        c8[0] = ci.x & 0xffff;  c8[1] = ci.x >> 16;
        c8[2] = ci.y & 0xffff;  c8[3] = ci.y >> 16;
        c8[4] = ci.z & 0xffff;  c8[5] = ci.z >> 16;
        c8[6] = ci.w & 0xffff;  c8[7] = ci.w >> 16;

        // merge duplicate cids into the first occurrence; duplicates -> dummy
#pragma unroll
        for (int j = 1; j < 8; ++j) {
            bool done = false;
#pragma unroll
            for (int i = 0; i < j; ++i) {
                bool eq = (c8[i] == c8[j]);
                v[i] += (eq && !done) ? v[j] : 0.f;
                done = done || eq;
            }
            c8[j] = done ? C_ : c8[j];
        }

        // batched non-atomic RMW: 8 reads, then 8 writes (distinct addresses)
        float old[8];
#pragma unroll
        for (int j = 0; j < 8; ++j) old[j] = aw[c8[j] * 64 + l];
#pragma unroll
        for (int j = 0; j < 8; ++j) aw[c8[j] * 64 + l] = old[j] + v[j];

#pragma unroll
        for (int j = 0; j < 8; ++j) v[j] = vn[j];
    }
    __syncthreads();

    // flush: sum the two row-half regions, store per-block partial
    float* pb = g_part + (size_t)bid * (2 * C_ * D_);
    for (int i = tid * 4; i < 2 * C_ * D_; i += B3_THREADS * 4) {
        const int ar = i >> 13;
        const int cd = i & (C_ * D_ - 1);
        const int c  = cd >> 7;
        const int d  = cd & 127;
        const int hh = d >> 6;
        const int dl = d & 63;
        const float* r0 = acc + ((ar * 2 + hh) * 2 + 0) * REG_STRIDE + c * 64 + dl;
        const float* r1 = acc + ((ar * 2 + hh) * 2 + 1) * REG_STRIDE + c * 64 + dl;
        float4 s0 = *(const float4*)r0;
        float4 s1 = *(const float4*)r1;
        float4 o;
        o.x = s0.x + s1.x; o.y = s0.y + s1.y;
        o.z = s0.z + s1.z; o.w = s0.w + s1.w;
        *(float4*)&pb[i] = o;
    }
    if (tid < C_) g_cnts[bid * C_ + tid] = cntL[tid];
}

// ---------------- Kernel C2: reduce partials + finalize --------------------
__global__ void finalize2_k(const float* __restrict__ ws,
                            const float* __restrict__ cen,
                            float* __restrict__ out) {
    int idx = blockIdx.x * blockDim.x + threadIdx.x;   // < B*C*D
    const int b  = idx >> 13;            // /8192
    const int cd = idx & (C_ * D_ - 1);
    const int c  = cd >> 7;
    const float* part = ws + WS2_PART_OFF;
    const float* cnts = ws + WS2_CNTS_OFF;

    float ks = 0.f, vs = 0.f, n = 0.f;
#pragma unroll
    for (int p = 0; p < 16; ++p) {
        const size_t pb = (size_t)(b * 16 + p) * (2 * C_ * D_);
        ks += part[pb + cd];
        vs += part[pb + C_ * D_ + cd];
        n  += cnts[(b * 16 + p) * C_ + c];
    }
    float cc, cv;
    if (n > 0.f) {
        cc = ks / n;
        cv = vs / n;
    } else {
        cc = cen[cd];
        cv = 0.f;
    }
    out[idx] = cc;
    out[B_ * C_ * D_ + idx] = cv;
}

// ---------------- fallback (atomic) path, used only if ws too small -------
constexpr int ACC_THREADS = 512;
constexpr int ACC_ROWS   = 256;
constexpr int ACC_NIT    = ACC_ROWS / 8;

__global__ __launch_bounds__(ACC_THREADS, 2) void accum_k(
    const float* __restrict__ keys, const float* __restrict__ values,
    const float* __restrict__ mask, const float* __restrict__ out_asg,
    float* __restrict__ g_ksum, float* __restrict__ g_vsum,
    float* __restrict__ g_cnt) {

    __shared__ float accK[C_ * D_];
    __shared__ float accV[C_ * D_];
    __shared__ float cntL[C_];
    __shared__ short cid[ACC_ROWS];

    const int tid = threadIdx.x;
    for (int i = tid; i < C_ * D_; i += ACC_THREADS) { accK[i] = 0.f; accV[i] = 0.f; }
    if (tid < C_) cntL[tid] = 0.f;
    __syncthreads();

    const int bid = blockIdx.x;
    const int batch = bid >> 5;
    const int srow0 = (bid & 31) * ACC_ROWS;
    const size_t rbase = (size_t)batch * S_ + srow0;

    if (tid < ACC_ROWS) {
        float mv = mask[rbase + tid];
        int a = (int)out_asg[rbase + tid];
        short s = (mv != 0.f) ? (short)a : (short)C_;
        cid[tid] = s;
        if (s < C_) atomicAdd(&cntL[s], 1.f);
    }
    __syncthreads();

    const int r_off = tid >> 6;
    const int half  = (tid >> 5) & 1;
    const int c4    = tid & 31;
    const float* src = (half ? values : keys) + (rbase + r_off) * D_ + c4 * 4;
    float* acc = half ? accV : accK;

    for (int it = 0; it < ACC_NIT; ++it) {
        float4 cur = *(const float4*)(src + (size_t)it * 8 * D_);
        const int a = cid[it * 8 + r_off];
        if (a < C_) {
            float* p = &acc[a * D_ + c4 * 4];
            atomicAdd(p + 0, cur.x);
            atomicAdd(p + 1, cur.y);
            atomicAdd(p + 2, cur.z);
            atomicAdd(p + 3, cur.w);
        }
    }
    __syncthreads();

    float* gks = g_ksum + (size_t)batch * C_ * D_;
    float* gvs = g_vsum + (size_t)batch * C_ * D_;
    for (int i = tid; i < C_ * D_; i += ACC_THREADS) {
        atomicAdd(&gks[i], accK[i]);
        atomicAdd(&gvs[i], accV[i]);
    }
    if (tid < C_) atomicAdd(&g_cnt[batch * C_ + tid], cntL[tid]);
}

__global__ void finalize_k(const float* __restrict__ ws,
                           const float* __restrict__ cen,
                           float* __restrict__ out) {
    int idx = blockIdx.x * blockDim.x + threadIdx.x;
    const float* ksum = ws + WS_KSUM_OFF;
    const float* vsum = ws + WS_VSUM_OFF;
    const float* cnt  = ws + WS_CNTS_OFF;
    int bc = idx >> 7;
    int cd = idx & (C_ * D_ - 1);
    float n = cnt[bc];
    float cc, cv;
    if (n > 0.f) {
        cc = ksum[idx] / n;
        cv = vsum[idx] / n;
    } else {
        cc = cen[cd];
        cv = 0.f;
    }
    out[idx] = cc;
    out[B_ * C_ * D_ + idx] = cv;
}

extern "C" void kernel_launch(void* const* d_in, const int* in_sizes, int n_in,
                              void* d_out, int out_size, void* d_ws, size_t ws_size,
                              hipStream_t stream) {
    const float* keys   = (const float*)d_in[0];
    const float* values = (const float*)d_in[1];
    const float* mask   = (const float*)d_in[2];
    const float* cen    = (const float*)d_in[3];
    float* ws  = (float*)d_ws;
    float* out = (float*)d_out;
    float* out_asg = out + 2 * B_ * C_ * D_;

    normalize_centroids_k<<<1, 512, 0, stream>>>(cen, ws + WS2_CNT_OFF);

    assign2_k<<<(B_ * S_) / A2_ROWS, A2_THREADS, 0, stream>>>(
        keys, mask, ws + WS2_CNT_OFF, out_asg);

    if (ws_size >= WS2_NEEDED_BYTES) {
        accum3_k<<<(B_ * S_) / B3_ROWS, B3_THREADS, 0, stream>>>(
            keys, values, mask, out_asg,
            ws + WS2_PART_OFF, ws + WS2_CNTS_OFF);
        finalize2_k<<<(B_ * C_ * D_) / 256, 256, 0, stream>>>(ws, cen, out);
    } else {
        hipMemsetAsync(ws + WS_KSUM_OFF, 0,
                       (size_t)(2 * B_ * C_ * D_ + B_ * C_) * sizeof(float), stream);
        accum_k<<<(B_ * S_) / ACC_ROWS, ACC_THREADS, 0, stream>>>(
            keys, values, mask, out_asg,
            ws + WS_KSUM_OFF, ws + WS_VSUM_OFF, ws + WS_CNTS_OFF);
        finalize_k<<<(B_ * C_ * D_) / 256, 256, 0, stream>>>(ws, cen, out);
    }
}